// Round 12
// baseline (255.965 us; speedup 1.0000x reference)
//
#include <hip/hip_runtime.h>
#include <math.h>

#define EMB 2048
#define NH 16
#define HD 128
#define BATCH 8
#define SEQ 16
#define KVLEN 4096
#define PARTS 16  /* flash chunks = 4 blocks x 4 waves */
#define MROWS (BATCH * SEQ) /* 128 */

typedef __attribute__((ext_vector_type(8))) short bf16x8;
typedef __attribute__((ext_vector_type(4))) float f32x4;

__device__ __forceinline__ unsigned cvtpk(float lo, float hi) {
  unsigned r;
  asm("v_cvt_pk_bf16_f32 %0, %1, %2" : "=v"(r) : "v"(lo), "v"(hi));
  return r;
}
__device__ __forceinline__ float blo(unsigned int w) {
  return __uint_as_float(w << 16);
}
__device__ __forceinline__ float bhi(unsigned int w) {
  return __uint_as_float(w & 0xffff0000u);
}
union U8 {
  uint4 u;
  bf16x8 v;
};
__device__ __forceinline__ bf16x8 pack8(float4 a, float4 b) {
  U8 r;
  r.u.x = cvtpk(a.x, a.y);
  r.u.y = cvtpk(a.z, a.w);
  r.u.z = cvtpk(b.x, b.y);
  r.u.w = cvtpk(b.z, b.w);
  return r.v;
}
// split 8 floats into bf16 high + bf16 residual fragments
__device__ __forceinline__ void split8(float4 a, float4 b, bf16x8* h,
                                       bf16x8* l) {
  U8 hh, ll;
  hh.u.x = cvtpk(a.x, a.y);
  hh.u.y = cvtpk(a.z, a.w);
  hh.u.z = cvtpk(b.x, b.y);
  hh.u.w = cvtpk(b.z, b.w);
  ll.u.x = cvtpk(a.x - blo(hh.u.x), a.y - bhi(hh.u.x));
  ll.u.y = cvtpk(a.z - blo(hh.u.y), a.w - bhi(hh.u.y));
  ll.u.z = cvtpk(b.x - blo(hh.u.z), b.y - bhi(hh.u.z));
  ll.u.w = cvtpk(b.z - blo(hh.u.w), b.w - bhi(hh.u.w));
  *h = hh.v;
  *l = ll.v;
}

// ---------------------------------------------------------------------------
// Pre-split x (fp32) -> Xh, Xl (bf16 row-major, same layout).
// ---------------------------------------------------------------------------
__global__ __launch_bounds__(256) void split_x_k(const float* __restrict__ x,
                                                 unsigned short* __restrict__ Xh,
                                                 unsigned short* __restrict__ Xl) {
  const int idx4 = blockIdx.x * 256 + threadIdx.x;  // 0..65535
  float4 a = ((const float4*)x)[idx4];
  unsigned h0 = cvtpk(a.x, a.y);
  unsigned h1 = cvtpk(a.z, a.w);
  unsigned l0 = cvtpk(a.x - blo(h0), a.y - bhi(h0));
  unsigned l1 = cvtpk(a.z - blo(h1), a.w - bhi(h1));
  ((uint2*)Xh)[idx4] = make_uint2(h0, h1);
  ((uint2*)Xl)[idx4] = make_uint2(l0, l1);
}

// ---------------------------------------------------------------------------
// bf16x3 MFMA GEMM: Y[r][d] = sum_c A[r][c] * W[d][c]  (+bias).
// A pre-split (Ah,Al bf16); W fp32, split in-flight. 3 MFMA passes:
// Ah*Wh + Ah*Wl + Al*Wh into one fp32 accumulator (xl*wl ~2^-18 dropped).
// Grid (EMB/32, 1, NM). 256 thr = 4 waves; wave w: rows w*32..+31, all 32
// block cols. No LDS, no barriers, waves independent.
// Frag layouts per m89/R11: A/B lane = row lane&15, k = (lane>>4)*8+j;
// D lane: col=lane&15 (B-row), row=(lane>>4)*4+reg (A-row).
// ---------------------------------------------------------------------------
template <bool BIAS>
__global__ __launch_bounds__(256) void gemm_bf3(
    const unsigned short* __restrict__ Ah_, const unsigned short* __restrict__ Al_,
    const float* __restrict__ W0, const float* __restrict__ W1,
    const float* __restrict__ W2, const float* __restrict__ bias,
    float* __restrict__ Y0, float* __restrict__ Y1, float* __restrict__ Y2) {
  const int z = blockIdx.z;
  const float* __restrict__ W = (z == 0) ? W0 : (z == 1) ? W1 : W2;
  float* __restrict__ Y = (z == 0) ? Y0 : (z == 1) ? Y1 : Y2;
  const int c0 = blockIdx.x * 32;
  const int tid = threadIdx.x;
  const int w = tid >> 6;
  const int lane = tid & 63;
  const int lr = lane & 15;
  const int lg = lane >> 4;
  const int m0 = w * 32;

  f32x4 acc[2][2];
#pragma unroll
  for (int mf = 0; mf < 2; ++mf)
#pragma unroll
    for (int nf = 0; nf < 2; ++nf) acc[mf][nf] = (f32x4){0.f, 0.f, 0.f, 0.f};

  const unsigned short* a0p = Ah_ + (size_t)(m0 + lr) * EMB + lg * 8;
  const unsigned short* a1p = Ah_ + (size_t)(m0 + 16 + lr) * EMB + lg * 8;
  const unsigned short* a0lp = Al_ + (size_t)(m0 + lr) * EMB + lg * 8;
  const unsigned short* a1lp = Al_ + (size_t)(m0 + 16 + lr) * EMB + lg * 8;
  const float* w0p = W + (size_t)(c0 + lr) * EMB + lg * 8;
  const float* w1p = W + (size_t)(c0 + 16 + lr) * EMB + lg * 8;

  for (int ks = 0; ks < 64; ++ks) {
    const int k0 = ks * 32;
    bf16x8 Ah[2], Al[2];
    Ah[0] = *(const bf16x8*)(a0p + k0);
    Ah[1] = *(const bf16x8*)(a1p + k0);
    Al[0] = *(const bf16x8*)(a0lp + k0);
    Al[1] = *(const bf16x8*)(a1lp + k0);
    bf16x8 Bh[2], Bl[2];
    {
      float4 b0 = ((const float4*)(w0p + k0))[0];
      float4 b1 = ((const float4*)(w0p + k0))[1];
      split8(b0, b1, &Bh[0], &Bl[0]);
      float4 c0v = ((const float4*)(w1p + k0))[0];
      float4 c1v = ((const float4*)(w1p + k0))[1];
      split8(c0v, c1v, &Bh[1], &Bl[1]);
    }
#pragma unroll
    for (int mf = 0; mf < 2; ++mf)
#pragma unroll
      for (int nf = 0; nf < 2; ++nf) {
        acc[mf][nf] = __builtin_amdgcn_mfma_f32_16x16x32_bf16(
            Ah[mf], Bh[nf], acc[mf][nf], 0, 0, 0);
        acc[mf][nf] = __builtin_amdgcn_mfma_f32_16x16x32_bf16(
            Ah[mf], Bl[nf], acc[mf][nf], 0, 0, 0);
        acc[mf][nf] = __builtin_amdgcn_mfma_f32_16x16x32_bf16(
            Al[mf], Bh[nf], acc[mf][nf], 0, 0, 0);
      }
  }

#pragma unroll
  for (int nf = 0; nf < 2; ++nf) {
    const int col = c0 + nf * 16 + lr;
    const float bv = BIAS ? bias[col] : 0.f;
#pragma unroll
    for (int mf = 0; mf < 2; ++mf)
#pragma unroll
      for (int r = 0; r < 4; ++r)
        Y[(size_t)(m0 + mf * 16 + lg * 4 + r) * EMB + col] =
            acc[mf][nf][r] + bv;
  }
}

// ---------------------------------------------------------------------------
// RoPE on yq (z=0) and yk (z=1), in place. Grid 512 x 256 (f4 elements).
// ---------------------------------------------------------------------------
__global__ __launch_bounds__(256) void rope_k(float* __restrict__ yq,
                                              float* __restrict__ yk) {
  const int idx4g = blockIdx.x * 256 + threadIdx.x;  // 0..131071
  const int z = idx4g >> 16;
  const int idx4 = idx4g & 65535;
  float* y = z ? yk : yq;
  const int idx = idx4 << 2;
  const int row = idx >> 11;
  const int col = idx & 2047;
  const float s = (float)(row & 15);
  const int hd = col & 127;
  const float a0 = s * powf(10000.0f, -(float)hd * (1.0f / 128.0f));
  const float a1 = s * powf(10000.0f, -(float)(hd + 2) * (1.0f / 128.0f));
  float sn0, cs0, sn1, cs1;
  sincosf(a0, &sn0, &cs0);
  sincosf(a1, &sn1, &cs1);
  float4 v = ((const float4*)y)[idx4];
  float4 r;
  r.x = v.x * cs0 - v.y * sn0;
  r.y = v.x * sn0 + v.y * cs0;
  r.z = v.z * cs1 - v.w * sn1;
  r.w = v.z * sn1 + v.w * cs1;
  ((float4*)y)[idx4] = r;
}

// ---------------------------------------------------------------------------
// MFMA flash-attention partial. (unchanged from R11 — working)
// ---------------------------------------------------------------------------
__global__ __launch_bounds__(256) void attn_mfma_k(
    const float* __restrict__ q, const float* __restrict__ knew,
    const float* __restrict__ vnew, const float* __restrict__ ck,
    const float* __restrict__ cv, const int* __restrict__ sp_ptr,
    float* __restrict__ po, float* __restrict__ pm, float* __restrict__ pl) {
  const int jb = blockIdx.x, h = blockIdx.y, b = blockIdx.z;
  const int tid = threadIdx.x;
  const int w = tid >> 6;
  const int lane = tid & 63;
  const int lr = lane & 15;
  const int lg = lane >> 4;
  const int jw = jb * 4 + w;
  const int sp = *sp_ptr;
  const int L = sp + SEQ;
  const int nT = (L + 63) >> 6;
  const int tA = (nT * jw) / PARTS;
  const int tB = (nT * (jw + 1)) / PARTS;

  __shared__ unsigned short Pl[4][16 * 72];
  unsigned short* Pw = &Pl[w][0];

  const float qscale = 0.08838834764831845f;  // 1/sqrt(128)

  bf16x8 Qf[4];
  {
    const float* qb = q + (size_t)(b * SEQ + lr) * EMB + h * HD + lg * 8;
#pragma unroll
    for (int kc = 0; kc < 4; ++kc) {
      float4 a = *(const float4*)&qb[kc * 32];
      float4 c = *(const float4*)&qb[kc * 32 + 4];
      a.x *= qscale; a.y *= qscale; a.z *= qscale; a.w *= qscale;
      c.x *= qscale; c.y *= qscale; c.z *= qscale; c.w *= qscale;
      Qf[kc] = pack8(a, c);
    }
  }

  f32x4 Oa[8];
#pragma unroll
  for (int nd = 0; nd < 8; ++nd) Oa[nd] = (f32x4){0.f, 0.f, 0.f, 0.f};
  float m[4] = {-1e30f, -1e30f, -1e30f, -1e30f};
  float l[4] = {0.f, 0.f, 0.f, 0.f};

  for (int t = tA; t < tB; ++t) {
    const int t0 = t << 6;

    f32x4 S[4];
#pragma unroll
    for (int nt = 0; nt < 4; ++nt) S[nt] = (f32x4){0.f, 0.f, 0.f, 0.f};
    const float* kb[4];
#pragma unroll
    for (int nt = 0; nt < 4; ++nt) {
      const int key = t0 + nt * 16 + lr;
      const int ke = min(key, L - 1);
      kb[nt] = ((ke < sp) ? ck + (size_t)(b * KVLEN + ke) * EMB
                          : knew + (size_t)(b * SEQ + ke - sp) * EMB) +
               h * HD + lg * 8;
    }
#pragma unroll
    for (int kc = 0; kc < 4; ++kc) {
#pragma unroll
      for (int nt = 0; nt < 4; ++nt) {
        float4 a = *(const float4*)&kb[nt][kc * 32];
        float4 c = *(const float4*)&kb[nt][kc * 32 + 4];
        S[nt] = __builtin_amdgcn_mfma_f32_16x16x32_bf16(Qf[kc], pack8(a, c),
                                                        S[nt], 0, 0, 0);
      }
    }
#pragma unroll
    for (int nt = 0; nt < 4; ++nt)
      if (t0 + nt * 16 + lr >= L) S[nt] = (f32x4){-3e38f, -3e38f, -3e38f, -3e38f};

#pragma unroll
    for (int r = 0; r < 4; ++r) {
      float tm = fmaxf(fmaxf(S[0][r], S[1][r]), fmaxf(S[2][r], S[3][r]));
      tm = fmaxf(tm, __shfl_xor(tm, 1));
      tm = fmaxf(tm, __shfl_xor(tm, 2));
      tm = fmaxf(tm, __shfl_xor(tm, 4));
      tm = fmaxf(tm, __shfl_xor(tm, 8));
      const float mn = fmaxf(m[r], tm);
      const float sc = __expf(m[r] - mn);
      float p0 = __expf(S[0][r] - mn);
      float p1 = __expf(S[1][r] - mn);
      float p2 = __expf(S[2][r] - mn);
      float p3 = __expf(S[3][r] - mn);
      float ls = p0 + p1 + p2 + p3;
      ls += __shfl_xor(ls, 1);
      ls += __shfl_xor(ls, 2);
      ls += __shfl_xor(ls, 4);
      ls += __shfl_xor(ls, 8);
      l[r] = l[r] * sc + ls;
      m[r] = mn;
#pragma unroll
      for (int nd = 0; nd < 8; ++nd) Oa[nd][r] *= sc;
      const int qrow = lg * 4 + r;
      Pw[qrow * 72 + 0 * 16 + lr] = (unsigned short)(cvtpk(p0, p0) & 0xffffu);
      Pw[qrow * 72 + 1 * 16 + lr] = (unsigned short)(cvtpk(p1, p1) & 0xffffu);
      Pw[qrow * 72 + 2 * 16 + lr] = (unsigned short)(cvtpk(p2, p2) & 0xffffu);
      Pw[qrow * 72 + 3 * 16 + lr] = (unsigned short)(cvtpk(p3, p3) & 0xffffu);
    }

#pragma unroll
    for (int kc2 = 0; kc2 < 2; ++kc2) {
      U8 pa;
      pa.u = *(const uint4*)&Pw[lr * 72 + kc2 * 32 + lg * 8];
      const float* vb[8];
#pragma unroll
      for (int jj = 0; jj < 8; ++jj) {
        const int key = t0 + kc2 * 32 + lg * 8 + jj;
        const int ke = min(key, L - 1);
        vb[jj] = ((ke < sp) ? cv + (size_t)(b * KVLEN + ke) * EMB
                            : vnew + (size_t)(b * SEQ + ke - sp) * EMB) +
                 h * HD + lr;
      }
#pragma unroll
      for (int nd = 0; nd < 8; ++nd) {
        const int off = nd * 16;
        U8 vf;
        vf.u.x = cvtpk(vb[0][off], vb[1][off]);
        vf.u.y = cvtpk(vb[2][off], vb[3][off]);
        vf.u.z = cvtpk(vb[4][off], vb[5][off]);
        vf.u.w = cvtpk(vb[6][off], vb[7][off]);
        Oa[nd] = __builtin_amdgcn_mfma_f32_16x16x32_bf16(pa.v, vf.v, Oa[nd],
                                                         0, 0, 0);
      }
    }
  }

  const size_t pair = (size_t)(b * NH + h);
  const size_t pb = (pair * PARTS + jw) * SEQ;
#pragma unroll
  for (int nd = 0; nd < 8; ++nd)
#pragma unroll
    for (int r = 0; r < 4; ++r)
      po[(pb + lg * 4 + r) * HD + nd * 16 + lr] = Oa[nd][r];
  if (lr == 0) {
#pragma unroll
    for (int r = 0; r < 4; ++r) {
      pm[pb + lg * 4 + r] = m[r];
      pl[pb + lg * 4 + r] = l[r];
    }
  }
}

// ---------------------------------------------------------------------------
// Combine PARTS partials -> attn as bf16 split (h,l) for the Wo MFMA GEMM.
// ---------------------------------------------------------------------------
__global__ __launch_bounds__(256) void combine_k(
    const float* __restrict__ po, const float* __restrict__ pm,
    const float* __restrict__ pl, unsigned short* __restrict__ attnH,
    unsigned short* __restrict__ attnL) {
  const int pair = blockIdx.x;
  const int b = pair >> 4, h = pair & 15;
  const int tid = threadIdx.x;
  const int d = tid & 127, gq = tid >> 7;
#pragma unroll
  for (int qi = 0; qi < 8; ++qi) {
    int qq = gq * 8 + qi;
    float Mx = -1e30f;
    float mj[PARTS], lj[PARTS];
#pragma unroll
    for (int jj = 0; jj < PARTS; ++jj) {
      mj[jj] = pm[((size_t)pair * PARTS + jj) * SEQ + qq];
      lj[jj] = pl[((size_t)pair * PARTS + jj) * SEQ + qq];
      Mx = fmaxf(Mx, mj[jj]);
    }
    float Ls = 0.f, o = 0.f;
#pragma unroll
    for (int jj = 0; jj < PARTS; ++jj) {
      float w = __expf(mj[jj] - Mx);
      Ls += lj[jj] * w;
      o += po[(((size_t)pair * PARTS + jj) * SEQ + qq) * HD + d] * w;
    }
    o /= Ls;
    const unsigned hp = cvtpk(o, o);
    const float lf = o - blo(hp);
    const unsigned lp = cvtpk(lf, lf);
    const size_t off = (size_t)(b * SEQ + qq) * EMB + h * HD + d;
    attnH[off] = (unsigned short)(hp & 0xffffu);
    attnL[off] = (unsigned short)(lp & 0xffffu);
  }
}

// ---------------------------------------------------------------------------
extern "C" void kernel_launch(void* const* d_in, const int* in_sizes, int n_in,
                              void* d_out, int out_size, void* d_ws,
                              size_t ws_size, hipStream_t stream) {
  const float* x = (const float*)d_in[0];
  const float* Wq = (const float*)d_in[1];
  const float* Wk = (const float*)d_in[2];
  const float* Wv = (const float*)d_in[3];
  const float* Wo = (const float*)d_in[4];
  const float* bo = (const float*)d_in[5];
  const float* ck = (const float*)d_in[6];
  const float* cv = (const float*)d_in[7];
  const int* sp = (const int*)d_in[8];
  float* out = (float*)d_out;

  float* ws = (float*)d_ws;
  const size_t U = 262144;  // 128*2048 floats
  float* yq = ws;
  float* yk = ws + U * 1;
  float* yv = ws + U * 2;
  unsigned short* Xh = (unsigned short*)(ws + U * 3);            // 0.5U floats
  unsigned short* Xl = (unsigned short*)(ws + U * 3 + U / 2);
  unsigned short* attnH = (unsigned short*)(ws + U * 4);
  unsigned short* attnL = (unsigned short*)(ws + U * 4 + U / 2);
  float* po = ws + U * 5;             // 16U -> [5,21)
  float* pm = ws + U * 21;            // 32768 floats
  float* pl = ws + U * 21 + 32768;

  // 1) split x -> bf16 h/l
  split_x_k<<<dim3(256), 256, 0, stream>>>(x, Xh, Xl);

  // 2) QKV projection (bf16x3 MFMA)
  gemm_bf3<false><<<dim3(64, 1, 3), 256, 0, stream>>>(
      Xh, Xl, Wq, Wk, Wv, nullptr, yq, yk, yv);

  // 3) RoPE on yq, yk (in place)
  rope_k<<<dim3(512), 256, 0, stream>>>(yq, yk);

  // 4) MFMA flash-attention partials (16 wave-chunks)
  attn_mfma_k<<<dim3(4, NH, BATCH), 256, 0, stream>>>(
      yq, yk, yv, ck, cv, sp, po, pm, pl);

  // 5) combine -> attn bf16 h/l
  combine_k<<<dim3(BATCH * NH), 256, 0, stream>>>(po, pm, pl, attnH, attnL);

  // 6) output projection (bf16x3 MFMA) + bias
  gemm_bf3<true><<<dim3(64, 1, 1), 256, 0, stream>>>(
      attnH, attnL, Wo, Wo, Wo, bo, out, out, out);

  (void)in_sizes; (void)n_in; (void)out_size; (void)ws_size;
}

// Round 13
// 157.312 us; speedup vs baseline: 1.6271x; 1.6271x over previous
//
#include <hip/hip_runtime.h>
#include <math.h>

#define EMB 2048
#define NH 16
#define HD 128
#define BATCH 8
#define SEQ 16
#define KVLEN 4096
#define PARTS 16  /* flash chunks = 4 blocks x 4 waves */
#define MROWS (BATCH * SEQ) /* 128 */

typedef __attribute__((ext_vector_type(8))) short bf16x8;
typedef __attribute__((ext_vector_type(4))) float f32x4;

__device__ __forceinline__ unsigned cvtpk(float lo, float hi) {
  unsigned r;
  asm("v_cvt_pk_bf16_f32 %0, %1, %2" : "=v"(r) : "v"(lo), "v"(hi));
  return r;
}
__device__ __forceinline__ float blo(unsigned int w) {
  return __uint_as_float(w << 16);
}
__device__ __forceinline__ float bhi(unsigned int w) {
  return __uint_as_float(w & 0xffff0000u);
}
union U8 {
  uint4 u;
  bf16x8 v;
};
__device__ __forceinline__ bf16x8 pack8(float4 a, float4 b) {
  U8 r;
  r.u.x = cvtpk(a.x, a.y);
  r.u.y = cvtpk(a.z, a.w);
  r.u.z = cvtpk(b.x, b.y);
  r.u.w = cvtpk(b.z, b.w);
  return r.v;
}
// split 8 floats into bf16 high + bf16 residual fragments
__device__ __forceinline__ void split8(float4 a, float4 b, bf16x8* h,
                                       bf16x8* l) {
  U8 hh, ll;
  hh.u.x = cvtpk(a.x, a.y);
  hh.u.y = cvtpk(a.z, a.w);
  hh.u.z = cvtpk(b.x, b.y);
  hh.u.w = cvtpk(b.z, b.w);
  ll.u.x = cvtpk(a.x - blo(hh.u.x), a.y - bhi(hh.u.x));
  ll.u.y = cvtpk(a.z - blo(hh.u.y), a.w - bhi(hh.u.y));
  ll.u.z = cvtpk(b.x - blo(hh.u.z), b.y - bhi(hh.u.z));
  ll.u.w = cvtpk(b.z - blo(hh.u.w), b.w - bhi(hh.u.w));
  *h = hh.v;
  *l = ll.v;
}

// ---------------------------------------------------------------------------
// Pre-split x (fp32) -> Xh, Xl (bf16 row-major, same layout).
// ---------------------------------------------------------------------------
__global__ __launch_bounds__(256) void split_x_k(const float* __restrict__ x,
                                                 unsigned short* __restrict__ Xh,
                                                 unsigned short* __restrict__ Xl) {
  const int idx4 = blockIdx.x * 256 + threadIdx.x;  // 0..65535
  float4 a = ((const float4*)x)[idx4];
  unsigned h0 = cvtpk(a.x, a.y);
  unsigned h1 = cvtpk(a.z, a.w);
  unsigned l0 = cvtpk(a.x - blo(h0), a.y - bhi(h0));
  unsigned l1 = cvtpk(a.z - blo(h1), a.w - bhi(h1));
  ((uint2*)Xh)[idx4] = make_uint2(h0, h1);
  ((uint2*)Xl)[idx4] = make_uint2(l0, l1);
}

// ---------------------------------------------------------------------------
// bf16x3 MFMA GEMM with split-K: Ypart[r][d] = sum_{c in slice} A[r][c]*W[d][c].
// A pre-split (Ah,Al bf16); W fp32, split in-flight. 3 MFMA per frag-pair:
// Ah*Wh + Ah*Wl + Al*Wh (xl*wl ~2^-18 dropped). Grid (64, KP, NM).
// 256 thr = 4 waves; wave w: rows w*32..+31, block cols c0..c0+31.
// No LDS, no barriers. Partial output Yp[(z*KP+kp)*MROWS*EMB + ...].
// ---------------------------------------------------------------------------
template <int KP>
__global__ __launch_bounds__(256) void gemm_bf3(
    const unsigned short* __restrict__ Ah_, const unsigned short* __restrict__ Al_,
    const float* __restrict__ W0, const float* __restrict__ W1,
    const float* __restrict__ W2, float* __restrict__ Yp) {
  const int z = blockIdx.z;
  const float* __restrict__ W = (z == 0) ? W0 : (z == 1) ? W1 : W2;
  const int kp = blockIdx.y;
  const int c0 = blockIdx.x * 32;
  const int kb0 = kp * (EMB / KP);
  constexpr int ITERS = EMB / KP / 32;
  const int tid = threadIdx.x;
  const int w = tid >> 6;
  const int lane = tid & 63;
  const int lr = lane & 15;
  const int lg = lane >> 4;
  const int m0 = w * 32;

  f32x4 acc[2][2];
#pragma unroll
  for (int mf = 0; mf < 2; ++mf)
#pragma unroll
    for (int nf = 0; nf < 2; ++nf) acc[mf][nf] = (f32x4){0.f, 0.f, 0.f, 0.f};

  const unsigned short* a0p = Ah_ + (size_t)(m0 + lr) * EMB + kb0 + lg * 8;
  const unsigned short* a1p = Ah_ + (size_t)(m0 + 16 + lr) * EMB + kb0 + lg * 8;
  const unsigned short* a0lp = Al_ + (size_t)(m0 + lr) * EMB + kb0 + lg * 8;
  const unsigned short* a1lp = Al_ + (size_t)(m0 + 16 + lr) * EMB + kb0 + lg * 8;
  const float* w0p = W + (size_t)(c0 + lr) * EMB + kb0 + lg * 8;
  const float* w1p = W + (size_t)(c0 + 16 + lr) * EMB + kb0 + lg * 8;

  for (int ks = 0; ks < ITERS; ++ks) {
    const int k0 = ks * 32;
    bf16x8 Ah[2], Al[2];
    Ah[0] = *(const bf16x8*)(a0p + k0);
    Ah[1] = *(const bf16x8*)(a1p + k0);
    Al[0] = *(const bf16x8*)(a0lp + k0);
    Al[1] = *(const bf16x8*)(a1lp + k0);
    bf16x8 Bh[2], Bl[2];
    {
      float4 b0 = ((const float4*)(w0p + k0))[0];
      float4 b1 = ((const float4*)(w0p + k0))[1];
      split8(b0, b1, &Bh[0], &Bl[0]);
      float4 c0v = ((const float4*)(w1p + k0))[0];
      float4 c1v = ((const float4*)(w1p + k0))[1];
      split8(c0v, c1v, &Bh[1], &Bl[1]);
    }
#pragma unroll
    for (int mf = 0; mf < 2; ++mf)
#pragma unroll
      for (int nf = 0; nf < 2; ++nf) {
        acc[mf][nf] = __builtin_amdgcn_mfma_f32_16x16x32_bf16(
            Ah[mf], Bh[nf], acc[mf][nf], 0, 0, 0);
        acc[mf][nf] = __builtin_amdgcn_mfma_f32_16x16x32_bf16(
            Ah[mf], Bl[nf], acc[mf][nf], 0, 0, 0);
        acc[mf][nf] = __builtin_amdgcn_mfma_f32_16x16x32_bf16(
            Al[mf], Bh[nf], acc[mf][nf], 0, 0, 0);
      }
  }

  float* Y = Yp + (size_t)(z * KP + kp) * MROWS * EMB;
#pragma unroll
  for (int nf = 0; nf < 2; ++nf) {
    const int col = c0 + nf * 16 + lr;
#pragma unroll
    for (int mf = 0; mf < 2; ++mf)
#pragma unroll
      for (int r = 0; r < 4; ++r)
        Y[(size_t)(m0 + mf * 16 + lg * 4 + r) * EMB + col] = acc[mf][nf][r];
  }
}

// ---------------------------------------------------------------------------
// Sum 4 split-K parts per matrix; apply RoPE to q,k (z=0,1); v plain.
// ---------------------------------------------------------------------------
__global__ __launch_bounds__(256) void sum_qkv_rope_k(
    const float* __restrict__ parts, float* __restrict__ yq,
    float* __restrict__ yk, float* __restrict__ yv) {
  const int idx4 = blockIdx.x * 256 + threadIdx.x;
  const int idx = idx4 << 2;
  const int row = idx >> 11;
  const int col = idx & 2047;
  const float s = (float)(row & 15);
  const int hd = col & 127;
  const float a0 = s * powf(10000.0f, -(float)hd * (1.0f / 128.0f));
  const float a1 = s * powf(10000.0f, -(float)(hd + 2) * (1.0f / 128.0f));
  float sn0, cs0, sn1, cs1;
  sincosf(a0, &sn0, &cs0);
  sincosf(a1, &sn1, &cs1);
  const float4* p = (const float4*)parts;
  float* outs[3] = {yq, yk, yv};
#pragma unroll
  for (int z = 0; z < 3; ++z) {
    float4 v = make_float4(0.f, 0.f, 0.f, 0.f);
#pragma unroll
    for (int k = 0; k < 4; ++k) {
      float4 a = p[((size_t)(z * 4 + k)) * 65536 + idx4];
      v.x += a.x; v.y += a.y; v.z += a.z; v.w += a.w;
    }
    if (z < 2) {
      float4 r;
      r.x = v.x * cs0 - v.y * sn0;
      r.y = v.x * sn0 + v.y * cs0;
      r.z = v.z * cs1 - v.w * sn1;
      r.w = v.z * sn1 + v.w * cs1;
      v = r;
    }
    ((float4*)outs[z])[idx4] = v;
  }
}

// ---------------------------------------------------------------------------
// sum 8 split-K parts + bias -> final output
// ---------------------------------------------------------------------------
__global__ __launch_bounds__(256) void sum8_bias_k(const float* __restrict__ parts,
                                                   const float* __restrict__ bo,
                                                   float* __restrict__ out) {
  const size_t idx = (size_t)blockIdx.x * 256 + threadIdx.x;
  float4 s = *(const float4*)&bo[(idx << 2) & 2047];
  const float4* p = (const float4*)parts;
#pragma unroll
  for (int k = 0; k < 8; ++k) {
    float4 v = p[(size_t)k * 65536 + idx];
    s.x += v.x; s.y += v.y; s.z += v.z; s.w += v.w;
  }
  ((float4*)out)[idx] = s;
}

// ---------------------------------------------------------------------------
// MFMA flash-attention partial. (unchanged from R11 — working)
// ---------------------------------------------------------------------------
__global__ __launch_bounds__(256) void attn_mfma_k(
    const float* __restrict__ q, const float* __restrict__ knew,
    const float* __restrict__ vnew, const float* __restrict__ ck,
    const float* __restrict__ cv, const int* __restrict__ sp_ptr,
    float* __restrict__ po, float* __restrict__ pm, float* __restrict__ pl) {
  const int jb = blockIdx.x, h = blockIdx.y, b = blockIdx.z;
  const int tid = threadIdx.x;
  const int w = tid >> 6;
  const int lane = tid & 63;
  const int lr = lane & 15;
  const int lg = lane >> 4;
  const int jw = jb * 4 + w;
  const int sp = *sp_ptr;
  const int L = sp + SEQ;
  const int nT = (L + 63) >> 6;
  const int tA = (nT * jw) / PARTS;
  const int tB = (nT * (jw + 1)) / PARTS;

  __shared__ unsigned short Pl[4][16 * 72];
  unsigned short* Pw = &Pl[w][0];

  const float qscale = 0.08838834764831845f;  // 1/sqrt(128)

  bf16x8 Qf[4];
  {
    const float* qb = q + (size_t)(b * SEQ + lr) * EMB + h * HD + lg * 8;
#pragma unroll
    for (int kc = 0; kc < 4; ++kc) {
      float4 a = *(const float4*)&qb[kc * 32];
      float4 c = *(const float4*)&qb[kc * 32 + 4];
      a.x *= qscale; a.y *= qscale; a.z *= qscale; a.w *= qscale;
      c.x *= qscale; c.y *= qscale; c.z *= qscale; c.w *= qscale;
      Qf[kc] = pack8(a, c);
    }
  }

  f32x4 Oa[8];
#pragma unroll
  for (int nd = 0; nd < 8; ++nd) Oa[nd] = (f32x4){0.f, 0.f, 0.f, 0.f};
  float m[4] = {-1e30f, -1e30f, -1e30f, -1e30f};
  float l[4] = {0.f, 0.f, 0.f, 0.f};

  for (int t = tA; t < tB; ++t) {
    const int t0 = t << 6;

    f32x4 S[4];
#pragma unroll
    for (int nt = 0; nt < 4; ++nt) S[nt] = (f32x4){0.f, 0.f, 0.f, 0.f};
    const float* kb[4];
#pragma unroll
    for (int nt = 0; nt < 4; ++nt) {
      const int key = t0 + nt * 16 + lr;
      const int ke = min(key, L - 1);
      kb[nt] = ((ke < sp) ? ck + (size_t)(b * KVLEN + ke) * EMB
                          : knew + (size_t)(b * SEQ + ke - sp) * EMB) +
               h * HD + lg * 8;
    }
#pragma unroll
    for (int kc = 0; kc < 4; ++kc) {
#pragma unroll
      for (int nt = 0; nt < 4; ++nt) {
        float4 a = *(const float4*)&kb[nt][kc * 32];
        float4 c = *(const float4*)&kb[nt][kc * 32 + 4];
        S[nt] = __builtin_amdgcn_mfma_f32_16x16x32_bf16(Qf[kc], pack8(a, c),
                                                        S[nt], 0, 0, 0);
      }
    }
#pragma unroll
    for (int nt = 0; nt < 4; ++nt)
      if (t0 + nt * 16 + lr >= L) S[nt] = (f32x4){-3e38f, -3e38f, -3e38f, -3e38f};

#pragma unroll
    for (int r = 0; r < 4; ++r) {
      float tm = fmaxf(fmaxf(S[0][r], S[1][r]), fmaxf(S[2][r], S[3][r]));
      tm = fmaxf(tm, __shfl_xor(tm, 1));
      tm = fmaxf(tm, __shfl_xor(tm, 2));
      tm = fmaxf(tm, __shfl_xor(tm, 4));
      tm = fmaxf(tm, __shfl_xor(tm, 8));
      const float mn = fmaxf(m[r], tm);
      const float sc = __expf(m[r] - mn);
      float p0 = __expf(S[0][r] - mn);
      float p1 = __expf(S[1][r] - mn);
      float p2 = __expf(S[2][r] - mn);
      float p3 = __expf(S[3][r] - mn);
      float ls = p0 + p1 + p2 + p3;
      ls += __shfl_xor(ls, 1);
      ls += __shfl_xor(ls, 2);
      ls += __shfl_xor(ls, 4);
      ls += __shfl_xor(ls, 8);
      l[r] = l[r] * sc + ls;
      m[r] = mn;
#pragma unroll
      for (int nd = 0; nd < 8; ++nd) Oa[nd][r] *= sc;
      const int qrow = lg * 4 + r;
      Pw[qrow * 72 + 0 * 16 + lr] = (unsigned short)(cvtpk(p0, p0) & 0xffffu);
      Pw[qrow * 72 + 1 * 16 + lr] = (unsigned short)(cvtpk(p1, p1) & 0xffffu);
      Pw[qrow * 72 + 2 * 16 + lr] = (unsigned short)(cvtpk(p2, p2) & 0xffffu);
      Pw[qrow * 72 + 3 * 16 + lr] = (unsigned short)(cvtpk(p3, p3) & 0xffffu);
    }

#pragma unroll
    for (int kc2 = 0; kc2 < 2; ++kc2) {
      U8 pa;
      pa.u = *(const uint4*)&Pw[lr * 72 + kc2 * 32 + lg * 8];
      const float* vb[8];
#pragma unroll
      for (int jj = 0; jj < 8; ++jj) {
        const int key = t0 + kc2 * 32 + lg * 8 + jj;
        const int ke = min(key, L - 1);
        vb[jj] = ((ke < sp) ? cv + (size_t)(b * KVLEN + ke) * EMB
                            : vnew + (size_t)(b * SEQ + ke - sp) * EMB) +
                 h * HD + lr;
      }
#pragma unroll
      for (int nd = 0; nd < 8; ++nd) {
        const int off = nd * 16;
        U8 vf;
        vf.u.x = cvtpk(vb[0][off], vb[1][off]);
        vf.u.y = cvtpk(vb[2][off], vb[3][off]);
        vf.u.z = cvtpk(vb[4][off], vb[5][off]);
        vf.u.w = cvtpk(vb[6][off], vb[7][off]);
        Oa[nd] = __builtin_amdgcn_mfma_f32_16x16x32_bf16(pa.v, vf.v, Oa[nd],
                                                         0, 0, 0);
      }
    }
  }

  const size_t pair = (size_t)(b * NH + h);
  const size_t pb = (pair * PARTS + jw) * SEQ;
#pragma unroll
  for (int nd = 0; nd < 8; ++nd)
#pragma unroll
    for (int r = 0; r < 4; ++r)
      po[(pb + lg * 4 + r) * HD + nd * 16 + lr] = Oa[nd][r];
  if (lr == 0) {
#pragma unroll
    for (int r = 0; r < 4; ++r) {
      pm[pb + lg * 4 + r] = m[r];
      pl[pb + lg * 4 + r] = l[r];
    }
  }
}

// ---------------------------------------------------------------------------
// Combine PARTS partials -> attn as bf16 split (h,l) for the Wo MFMA GEMM.
// ---------------------------------------------------------------------------
__global__ __launch_bounds__(256) void combine_k(
    const float* __restrict__ po, const float* __restrict__ pm,
    const float* __restrict__ pl, unsigned short* __restrict__ attnH,
    unsigned short* __restrict__ attnL) {
  const int pair = blockIdx.x;
  const int b = pair >> 4, h = pair & 15;
  const int tid = threadIdx.x;
  const int d = tid & 127, gq = tid >> 7;
#pragma unroll
  for (int qi = 0; qi < 8; ++qi) {
    int qq = gq * 8 + qi;
    float Mx = -1e30f;
    float mj[PARTS], lj[PARTS];
#pragma unroll
    for (int jj = 0; jj < PARTS; ++jj) {
      mj[jj] = pm[((size_t)pair * PARTS + jj) * SEQ + qq];
      lj[jj] = pl[((size_t)pair * PARTS + jj) * SEQ + qq];
      Mx = fmaxf(Mx, mj[jj]);
    }
    float Ls = 0.f, o = 0.f;
#pragma unroll
    for (int jj = 0; jj < PARTS; ++jj) {
      float w = __expf(mj[jj] - Mx);
      Ls += lj[jj] * w;
      o += po[(((size_t)pair * PARTS + jj) * SEQ + qq) * HD + d] * w;
    }
    o /= Ls;
    const unsigned hp = cvtpk(o, o);
    const float lf = o - blo(hp);
    const unsigned lp = cvtpk(lf, lf);
    const size_t off = (size_t)(b * SEQ + qq) * EMB + h * HD + d;
    attnH[off] = (unsigned short)(hp & 0xffffu);
    attnL[off] = (unsigned short)(lp & 0xffffu);
  }
}

// ---------------------------------------------------------------------------
extern "C" void kernel_launch(void* const* d_in, const int* in_sizes, int n_in,
                              void* d_out, int out_size, void* d_ws,
                              size_t ws_size, hipStream_t stream) {
  const float* x = (const float*)d_in[0];
  const float* Wq = (const float*)d_in[1];
  const float* Wk = (const float*)d_in[2];
  const float* Wv = (const float*)d_in[3];
  const float* Wo = (const float*)d_in[4];
  const float* bo = (const float*)d_in[5];
  const float* ck = (const float*)d_in[6];
  const float* cv = (const float*)d_in[7];
  const int* sp = (const int*)d_in[8];
  float* out = (float*)d_out;

  float* ws = (float*)d_ws;
  const size_t U = 262144;  // 128*2048 floats
  float* yq = ws;
  float* yk = ws + U * 1;
  float* yv = ws + U * 2;
  unsigned short* Xh = (unsigned short*)(ws + U * 3);
  unsigned short* Xl = (unsigned short*)(ws + U * 3 + U / 2);
  unsigned short* attnH = (unsigned short*)(ws + U * 4);
  unsigned short* attnL = (unsigned short*)(ws + U * 4 + U / 2);
  float* po = ws + U * 5;              // 16U -> [5,21)
  float* pm = ws + U * 21;             // 32768 floats
  float* pl = ws + U * 21 + 32768;
  float* qkvParts = ws + U * 22;       // 12U -> [22,34)
  float* woParts = ws + U * 34;        // 8U -> [34,42)

  // 1) split x -> bf16 h/l
  split_x_k<<<dim3(256), 256, 0, stream>>>(x, Xh, Xl);

  // 2) QKV projection (bf16x3 MFMA, split-K=4: 768 blocks)
  gemm_bf3<4><<<dim3(64, 4, 3), 256, 0, stream>>>(Xh, Xl, Wq, Wk, Wv,
                                                  qkvParts);

  // 3) sum 4 parts + fused RoPE on q,k
  sum_qkv_rope_k<<<dim3(256), 256, 0, stream>>>(qkvParts, yq, yk, yv);

  // 4) MFMA flash-attention partials (16 wave-chunks)
  attn_mfma_k<<<dim3(4, NH, BATCH), 256, 0, stream>>>(
      yq, yk, yv, ck, cv, sp, po, pm, pl);

  // 5) combine -> attn bf16 h/l
  combine_k<<<dim3(BATCH * NH), 256, 0, stream>>>(po, pm, pl, attnH, attnL);

  // 6) output projection (bf16x3 MFMA, split-K=8: 512 blocks)
  gemm_bf3<8><<<dim3(64, 8, 1), 256, 0, stream>>>(attnH, attnL, Wo, Wo, Wo,
                                                  woParts);

  // 7) sum 8 parts + bias -> out
  sum8_bias_k<<<dim3(256), 256, 0, stream>>>(woParts, bo, out);

  (void)in_sizes; (void)n_in; (void)out_size; (void)ws_size;
}